// Round 3
// baseline (423.075 us; speedup 1.0000x reference)
//
#include <hip/hip_runtime.h>
#include <math.h>

#define SS 1024
#define DD 1024
#define NB 64
#define NT 34            // 33 tags + BOS
#define NP 48            // padded state count (3 x 16)
#define NC 32            // time chunks per sequence (32 steps each)
#define BOSR 33

typedef __attribute__((ext_vector_type(8))) short bf16x8;
typedef __attribute__((ext_vector_type(4))) float f32x4;

// ---- ws layout (float index) ----
#define WS_BOS   0                              // [65536] proj col 33
#define WS_PMAT  (WS_BOS + NB*SS)               // [64*32*2304] chunk matrices f32
#define WS_CC    (WS_PMAT + NB*NC*NP*NP)        // [2048] chunk log-renorm
#define WS_Z     (WS_CC + NB*NC)                // [64]
#define WS_SC    (WS_Z + NB)                    // [64]
#define WS_BF16  (WS_SC + NB)                   // bf16 region start (ushort*)
// bf16 region (ushort offsets)
#define BW_WT    0                              // Wt[48][1024]: W^T bf16, pad 0
#define BW_ETA   (48*1024)                      // expTA[48][64]: A[m][k]=exp(T[k][m])

__device__ __forceinline__ float warp_sum64(float x) {
  #pragma unroll
  for (int off = 32; off > 0; off >>= 1) x += __shfl_down(x, off, 64);
  return x;
}
__device__ __forceinline__ float rfl(float x) {
  return __int_as_float(__builtin_amdgcn_readfirstlane(__float_as_int(x)));
}
__device__ __forceinline__ unsigned short f2bf(float f) {  // RNE (prep only)
  unsigned int u = __float_as_uint(f);
  unsigned int r = u + 0x7fffu + ((u >> 16) & 1u);
  return (unsigned short)(r >> 16);
}
__device__ __forceinline__ float bf2f(unsigned short h) {
  return __uint_as_float(((unsigned int)h) << 16);
}
// 2x f32 -> packed 2x bf16 in one VALU op (gfx950 v_cvt_pk_bf16_f32, RNE)
__device__ __forceinline__ unsigned int pk_bf16(float a, float b) {
  unsigned int d;
  asm("v_cvt_pk_bf16_f32 %0, %1, %2" : "=v"(d) : "v"(a), "v"(b));
  return d;
}

// ---------------- prep: Wt bf16 transpose + expTA ----------------------------
__global__ __launch_bounds__(256) void prep(const float* __restrict__ W,
                                            const float* __restrict__ T,
                                            unsigned short* __restrict__ bw) {
  int idx = blockIdx.x * 256 + threadIdx.x;
  if (idx < 48 * 1024) {                        // Wt[n][k] = W[k][n]
    int n = idx >> 10, k = idx & 1023;
    float v = (n < NT) ? W[k * NT + n] : 0.0f;
    bw[BW_WT + idx] = f2bf(v);
  } else if (idx < 48 * 1024 + 48 * 64) {       // expTA[m][k] = exp(T[k][m])
    int j = idx - 48 * 1024;
    int m = j >> 6, k = j & 63;
    float v = (m < NT && k < NT) ? __expf(T[k * NT + m]) : 0.0f;
    bw[BW_ETA + j] = f2bf(v);
  }
}

// ---------------- fused GEMM + chunk chains ----------------------------------
// 512 blocks x 256 thr; block = 128 rows of one batch (= 4 chunks of 32 steps).
// GEMM phase: direct-to-register A (each wave loads its own 32 rows), bf16 via
// cvt_pk, Wt B-frags from L2. NO LDS staging, NO barriers.
// Chain phase: wave w owns global chunk cg = 4*(blk&7)+w covering steps
// [32cg, 32cg+31] (step 0 dropped via ballot bit). ee comes straight from the
// wave's accumulators -> per-wave LDS slab; 32-step MFMA recurrence entirely
// wave-private (DS ops in-order per wave -> no __syncthreads anywhere).
__global__ __launch_bounds__(256) void gemm_chains(
    const float* __restrict__ em, const unsigned short* __restrict__ bw,
    const float* __restrict__ bias, const float* __restrict__ mask,
    float* __restrict__ logits, float* __restrict__ bos,
    float* __restrict__ Pmat, float* __restrict__ CC) {
  __shared__ float eeL[4][32][52];              // per-wave exp(proj), pad 52
  __shared__ unsigned short S[4][48][72];       // per-wave P bf16, stride 72
  const int tid = threadIdx.x;
  const int lane = tid & 63, wv = tid >> 6;
  const int q = lane >> 4, l15 = lane & 15;
  const size_t row0 = (size_t)blockIdx.x * 128;
  const int b = (int)(row0 >> 10);
  const int cg = (((int)(row0 & 1023)) >> 5) + wv;   // global chunk 0..31
  const unsigned short* Wt = bw + BW_WT;

  // ---- GEMM phase ----
  const float* A0 = em + (row0 + (size_t)wv * 32 + l15) * DD + q * 8;

  f32x4 acc[2][3];
  f32x4 z4 = {0.f, 0.f, 0.f, 0.f};
  #pragma unroll
  for (int mt = 0; mt < 2; ++mt)
    #pragma unroll
    for (int nt = 0; nt < 3; ++nt) acc[mt][nt] = z4;

  f32x4 p0a = __builtin_nontemporal_load((const f32x4*)(A0));
  f32x4 p0b = __builtin_nontemporal_load((const f32x4*)(A0 + 4));
  f32x4 p1a = __builtin_nontemporal_load((const f32x4*)(A0 + 16 * DD));
  f32x4 p1b = __builtin_nontemporal_load((const f32x4*)(A0 + 16 * DD + 4));
  bf16x8 Bf[3], Bn[3];
  #pragma unroll
  for (int nt = 0; nt < 3; ++nt)
    Bf[nt] = *(const bf16x8*)(Wt + (nt * 16 + l15) * 1024 + q * 8);

  for (int c = 0; c < 32; ++c) {
    int cn = (c + 1 < 32 ? c + 1 : c) * 32;     // next-chunk col offset
    f32x4 n0a = __builtin_nontemporal_load((const f32x4*)(A0 + cn));
    f32x4 n0b = __builtin_nontemporal_load((const f32x4*)(A0 + cn + 4));
    f32x4 n1a = __builtin_nontemporal_load((const f32x4*)(A0 + 16 * DD + cn));
    f32x4 n1b = __builtin_nontemporal_load((const f32x4*)(A0 + 16 * DD + cn + 4));
    #pragma unroll
    for (int nt = 0; nt < 3; ++nt)
      Bn[nt] = *(const bf16x8*)(Wt + (nt * 16 + l15) * 1024 + cn + q * 8);
    union { unsigned int u[4]; bf16x8 v; } c0, c1;
    c0.u[0] = pk_bf16(p0a[0], p0a[1]); c0.u[1] = pk_bf16(p0a[2], p0a[3]);
    c0.u[2] = pk_bf16(p0b[0], p0b[1]); c0.u[3] = pk_bf16(p0b[2], p0b[3]);
    c1.u[0] = pk_bf16(p1a[0], p1a[1]); c1.u[1] = pk_bf16(p1a[2], p1a[3]);
    c1.u[2] = pk_bf16(p1b[0], p1b[1]); c1.u[3] = pk_bf16(p1b[2], p1b[3]);
    bf16x8 Af0 = c0.v, Af1 = c1.v;
    #pragma unroll
    for (int nt = 0; nt < 3; ++nt) {
      acc[0][nt] = __builtin_amdgcn_mfma_f32_16x16x32_bf16(Af0, Bf[nt], acc[0][nt], 0, 0, 0);
      acc[1][nt] = __builtin_amdgcn_mfma_f32_16x16x32_bf16(Af1, Bf[nt], acc[1][nt], 0, 0, 0);
    }
    p0a = n0a; p0b = n0b; p1a = n1a; p1b = n1b;
    #pragma unroll
    for (int nt = 0; nt < 3; ++nt) Bf[nt] = Bn[nt];
  }

  // ---- epilogue: bias, store logits/bos, ee -> per-wave LDS ----
  #pragma unroll
  for (int nt = 0; nt < 3; ++nt) {
    int col = nt * 16 + l15;
    float bj = (col < NT) ? bias[col] : 0.0f;
    #pragma unroll
    for (int mt = 0; mt < 2; ++mt) {
      #pragma unroll
      for (int r = 0; r < 4; ++r) {
        float v = acc[mt][nt][r] + bj;
        size_t rg = row0 + wv * 32 + mt * 16 + q * 4 + r;
        if (col < 33) logits[rg * 33 + col] = v;
        else if (col == 33) bos[rg] = v;
        eeL[wv][mt * 16 + q * 4 + r][col] = (col < NT) ? __expf(v) : 0.0f;
      }
    }
  }

  float mval = 0.0f;                            // step-active mask for this chunk
  if (lane < 32) mval = mask[row0 + wv * 32 + lane];
  unsigned long long mb = __ballot(mval > 0.5f);
  if (cg == 0) mb &= ~1ull;                     // step 0 is in alpha_0

  {                                             // zero per-wave S then identity
    unsigned long long* p = (unsigned long long*)&S[wv][0][0];  // 864 qwords
    for (int i = lane; i < 864; i += 64) p[i] = 0ull;
  }
  if (lane < NT) S[wv][lane][lane] = 0x3F80;    // bf16(1.0)

  bf16x8 Ef[3][2];                              // static A = expT^T frags
  const unsigned short* eta = bw + BW_ETA;
  #pragma unroll
  for (int mt = 0; mt < 3; ++mt)
    #pragma unroll
    for (int kt = 0; kt < 2; ++kt)
      Ef[mt][kt] = *(const bf16x8*)(eta + (mt * 16 + l15) * 64 + kt * 32 + q * 8);

  float Clog = 0.0f;
  for (int tt = 0; tt < 32; ++tt) {
    if ((mb >> tt) & 1ull) {                    // SALU bit test, wave-uniform
      bf16x8 Bq[2][3];
      #pragma unroll
      for (int kt = 0; kt < 2; ++kt)
        #pragma unroll
        for (int nt = 0; nt < 3; ++nt)
          Bq[kt][nt] = *(const bf16x8*)&S[wv][nt * 16 + l15][kt * 32 + q * 8];
      f32x4 pacc[3][3];
      #pragma unroll
      for (int mt = 0; mt < 3; ++mt)
        #pragma unroll
        for (int nt = 0; nt < 3; ++nt) {
          pacc[mt][nt] = __builtin_amdgcn_mfma_f32_16x16x32_bf16(
              Ef[mt][0], Bq[0][nt], z4, 0, 0, 0);
          pacc[mt][nt] = __builtin_amdgcn_mfma_f32_16x16x32_bf16(
              Ef[mt][1], Bq[1][nt], pacc[mt][nt], 0, 0, 0);
        }
      float r = rfl(pacc[0][0][0]);             // P_new[0][0] > 0
      float rin = __builtin_amdgcn_rcpf(r);
      Clog += __logf(r);
      #pragma unroll
      for (int mt = 0; mt < 3; ++mt) {
        f32x4 e4 = *(const f32x4*)&eeL[wv][tt][mt * 16 + q * 4];
        e4 = e4 * rin;                          // combined col-scale * renorm
        #pragma unroll
        for (int nt = 0; nt < 3; ++nt) {
          f32x4 v = pacc[mt][nt] * e4;
          uint2 pk;
          pk.x = pk_bf16(v[0], v[1]);
          pk.y = pk_bf16(v[2], v[3]);
          *(uint2*)&S[wv][nt * 16 + l15][mt * 16 + q * 4] = pk;
        }
      }
    }
  }

  float* Pb = Pmat + (size_t)(b * NC + cg) * (NP * NP);
  #pragma unroll
  for (int i = 0; i < 9; ++i) {                 // dump S -> f32 Pmat
    int flat = i * 64 + lane;                   // 0..575 float4 slots
    int n = flat / 12, qq = flat - n * 12;
    unsigned long long pk = *(unsigned long long*)&S[wv][n][qq * 4];
    float4 o;
    o.x = bf2f((unsigned short)(pk));
    o.y = bf2f((unsigned short)(pk >> 16));
    o.z = bf2f((unsigned short)(pk >> 32));
    o.w = bf2f((unsigned short)(pk >> 48));
    *(float4*)&Pb[n * 48 + qq * 4] = o;
  }
  if (lane == 0) CC[b * NC + cg] = Clog;
}

// ---------------- per-batch serial combine + score (2 waves) -----------------
// wave 0: Z_b serial combine with register-prefetched Pmat + shfl'd CC.
// wave 1: supervised path score. No barriers (per-wave LDS is in-order).
__global__ __launch_bounds__(128) void reduceZ(
    const float* __restrict__ logits, const float* __restrict__ bos,
    const float* __restrict__ T, const float* __restrict__ Pmat,
    const float* __restrict__ CC, const int* __restrict__ tags,
    const float* __restrict__ mask, float* __restrict__ Zarr,
    float* __restrict__ scorearr) {
  const int b = blockIdx.x;
  const int tid = threadIdx.x;
  const int lane = tid & 63;

  if (tid >= 64) {                              // ---- score wave ----
    float local = 0.0f;
    for (int t = lane; t < SS; t += 64) {
      if (t == 0) {
        int tg = tags[b * SS];
        local += T[BOSR * NT + tg] + logits[(size_t)(b * SS) * 33 + tg];
      } else {
        int tg = tags[b * SS + t];
        int tp = tags[b * SS + t - 1];
        float m = mask[b * SS + t];
        local += m * (logits[(size_t)(b * SS + t) * 33 + tg] + T[tp * NT + tg]);
      }
    }
    float w = warp_sum64(local);
    if (lane == 0) scorearr[b] = w;
    return;
  }

  __shared__ __align__(16) float shv[64];
  float a0;
  if (lane < 33)       a0 = logits[(size_t)b * SS * 33 + lane] + T[BOSR * NT + lane];
  else if (lane == 33) a0 = bos[(size_t)b * SS] + T[BOSR * NT + 33];
  else                 a0 = -INFINITY;
  float K = rfl(a0);                            // lane0 finite
  float v = (lane < 48) ? __expf(a0 - K) : 0.0f;
  float C = K;
  float CCl = (lane < 32) ? CC[b * NC + lane] : 0.0f;
  const float* Pbase = Pmat + (size_t)b * NC * (NP * NP) + lane * 48;

  f32x4 Pp[12];                                 // prefetched chunk rows
  if (lane < 48) {
    #pragma unroll
    for (int i = 0; i < 12; ++i) Pp[i] = *(const f32x4*)(Pbase + i * 4);
  }
  for (int c = 0; c < NC; ++c) {
    shv[lane] = v;                              // in-order per wave
    f32x4 cur[12];
    #pragma unroll
    for (int i = 0; i < 12; ++i) cur[i] = Pp[i];
    if (c + 1 < NC && lane < 48) {              // prefetch next chunk
      #pragma unroll
      for (int i = 0; i < 12; ++i)
        Pp[i] = *(const f32x4*)(Pbase + (size_t)(c + 1) * (NP * NP) + i * 4);
    }
    float u = 0.0f;
    if (lane < 48) {
      float uu0 = 0.f, uu1 = 0.f, uu2 = 0.f, uu3 = 0.f;
      #pragma unroll
      for (int qq = 0; qq < 12; qq += 4) {
        f32x4 v0 = *(const f32x4*)&shv[qq * 4];
        f32x4 v1 = *(const f32x4*)&shv[qq * 4 + 4];
        f32x4 v2 = *(const f32x4*)&shv[qq * 4 + 8];
        f32x4 v3 = *(const f32x4*)&shv[qq * 4 + 12];
        uu0 = fmaf(cur[qq][0], v0[0], uu0);   uu0 = fmaf(cur[qq][1], v0[1], uu0);
        uu0 = fmaf(cur[qq][2], v0[2], uu0);   uu0 = fmaf(cur[qq][3], v0[3], uu0);
        uu1 = fmaf(cur[qq+1][0], v1[0], uu1); uu1 = fmaf(cur[qq+1][1], v1[1], uu1);
        uu1 = fmaf(cur[qq+1][2], v1[2], uu1); uu1 = fmaf(cur[qq+1][3], v1[3], uu1);
        uu2 = fmaf(cur[qq+2][0], v2[0], uu2); uu2 = fmaf(cur[qq+2][1], v2[1], uu2);
        uu2 = fmaf(cur[qq+2][2], v2[2], uu2); uu2 = fmaf(cur[qq+2][3], v2[3], uu2);
        uu3 = fmaf(cur[qq+3][0], v3[0], uu3); uu3 = fmaf(cur[qq+3][1], v3[1], uu3);
        uu3 = fmaf(cur[qq+3][2], v3[2], uu3); uu3 = fmaf(cur[qq+3][3], v3[3], uu3);
      }
      u = (uu0 + uu1) + (uu2 + uu3);
    }
    float r = rfl(u);                           // lane0: u > 0
    v = u * __builtin_amdgcn_rcpf(r);
    C += __logf(r) + __shfl(CCl, c, 64);
  }
  float s = warp_sum64(v);
  if (lane == 0) Zarr[b] = C + __logf(s);
}

// ---------------- final: loss = sum_b (Z_b - score_b) ------------------------
__global__ void finalk(const float* __restrict__ Zarr,
                       const float* __restrict__ sc, float* __restrict__ out) {
  float x = Zarr[threadIdx.x] - sc[threadIdx.x];
  float s = warp_sum64(x);
  if (threadIdx.x == 0) out[0] = s;
}

extern "C" void kernel_launch(void* const* d_in, const int* in_sizes, int n_in,
                              void* d_out, int out_size, void* d_ws, size_t ws_size,
                              hipStream_t stream) {
  const float* em   = (const float*)d_in[0];
  const int*   tags = (const int*)d_in[1];
  const float* mask = (const float*)d_in[2];
  const float* W    = (const float*)d_in[3];
  const float* bias = (const float*)d_in[4];
  const float* T    = (const float*)d_in[5];

  float* out = (float*)d_out;
  float* ws  = (float*)d_ws;
  float* bos   = ws + WS_BOS;
  float* Pmat  = ws + WS_PMAT;
  float* CC    = ws + WS_CC;
  float* Zarr  = ws + WS_Z;
  float* score = ws + WS_SC;
  unsigned short* bw = (unsigned short*)(ws + WS_BF16);
  float* logits = out + 1;                      // d_out = [loss, logits(B,S,33)]

  hipLaunchKernelGGL(prep, dim3(204), dim3(256), 0, stream, W, T, bw);
  hipLaunchKernelGGL(gemm_chains, dim3(NB * SS / 128), dim3(256), 0, stream,
                     em, bw, bias, mask, logits, bos, Pmat, CC);
  hipLaunchKernelGGL(reduceZ, dim3(NB), dim3(128), 0, stream,
                     logits, bos, T, Pmat, CC, tags, mask, Zarr, score);
  hipLaunchKernelGGL(finalk, dim3(1), dim3(64), 0, stream, Zarr, score, out);
}

// Round 4
// 417.137 us; speedup vs baseline: 1.0142x; 1.0142x over previous
//
#include <hip/hip_runtime.h>
#include <math.h>

#define SS 1024
#define DD 1024
#define NB 64
#define NT 34            // 33 tags + BOS
#define NP 48            // padded state count (3 x 16)
#define NC 32            // time chunks per sequence (32 steps each)
#define BOSR 33

typedef __attribute__((ext_vector_type(8))) short bf16x8;
typedef __attribute__((ext_vector_type(4))) float f32x4;

// ---- ws layout (float index) ----
#define WS_BOS   0                              // [65536] proj col 33
#define WS_PMAT  (WS_BOS + NB*SS)               // [64*32*2304] chunk matrices f32
#define WS_CC    (WS_PMAT + NB*NC*NP*NP)        // [2048] chunk log-renorm
#define WS_Z     (WS_CC + NB*NC)                // [64]
#define WS_SC    (WS_Z + NB)                    // [64]
#define WS_BF16  (WS_SC + NB)                   // bf16 region start (ushort*)
// bf16 region (ushort offsets)
#define BW_WT    0                              // Wt[48][1024]: W^T bf16, pad 0
#define BW_ETA   (48*1024)                      // expTA[48][64]: A[m][k]=exp(T[k][m])

__device__ __forceinline__ float warp_sum64(float x) {
  #pragma unroll
  for (int off = 32; off > 0; off >>= 1) x += __shfl_down(x, off, 64);
  return x;
}
__device__ __forceinline__ float rfl(float x) {
  return __int_as_float(__builtin_amdgcn_readfirstlane(__float_as_int(x)));
}
__device__ __forceinline__ unsigned short f2bf(float f) {  // RNE (prep only)
  unsigned int u = __float_as_uint(f);
  unsigned int r = u + 0x7fffu + ((u >> 16) & 1u);
  return (unsigned short)(r >> 16);
}
__device__ __forceinline__ float bf2f(unsigned short h) {
  return __uint_as_float(((unsigned int)h) << 16);
}
// 2x f32 -> packed 2x bf16 in one VALU op (gfx950 v_cvt_pk_bf16_f32, RNE)
__device__ __forceinline__ unsigned int pk_bf16(float a, float b) {
  unsigned int d;
  asm("v_cvt_pk_bf16_f32 %0, %1, %2" : "=v"(d) : "v"(a), "v"(b));
  return d;
}
// barrier that drains ONLY LDS ops (keeps global prefetch in flight; the
// compiler emits its own counted vmcnt before pf[] consumption)
__device__ __forceinline__ void lds_barrier() {
  asm volatile("s_waitcnt lgkmcnt(0)" ::: "memory");
  __builtin_amdgcn_s_barrier();
  __builtin_amdgcn_sched_barrier(0);
}

// ---------------- prep: Wt bf16 transpose + expTA ----------------------------
__global__ __launch_bounds__(256) void prep(const float* __restrict__ W,
                                            const float* __restrict__ T,
                                            unsigned short* __restrict__ bw) {
  int idx = blockIdx.x * 256 + threadIdx.x;
  if (idx < 48 * 1024) {                        // Wt[n][k] = W[k][n]
    int n = idx >> 10, k = idx & 1023;
    float v = (n < NT) ? W[k * NT + n] : 0.0f;
    bw[BW_WT + idx] = f2bf(v);
  } else if (idx < 48 * 1024 + 48 * 64) {       // expTA[m][k] = exp(T[k][m])
    int j = idx - 48 * 1024;
    int m = j >> 6, k = j & 63;
    float v = (m < NT && k < NT) ? __expf(T[k * NT + m]) : 0.0f;
    bw[BW_ETA + j] = f2bf(v);
  }
}

// ---------------- GEMM: proj = em @ W + b  (bf16 MFMA, mem-bound) ------------
// 512 blocks x 256 thr; block = 128 rows; wave w: rows w*32..+31 (2 Mtiles),
// 3 Ntiles (48 cols). em f32 -> bf16 staged via double-buffered LDS; W from
// precomputed bf16 Wt (global, L2-resident) prefetched into B-frags.
// Barrier = lds_barrier(): lgkmcnt-only, so the c+1 global prefetch is NOT
// drained at the chunk boundary (removes the vmcnt(0)-before-s_barrier stall).
__global__ __launch_bounds__(256) void gemm_mfma(
    const float* __restrict__ em, const unsigned short* __restrict__ bw,
    const float* __restrict__ bias,
    float* __restrict__ logits, float* __restrict__ bos) {
  __shared__ unsigned short At[2][128][40];     // row stride 40 bf16: 2-way max
  const int tid = threadIdx.x;
  const int lane = tid & 63, wv = tid >> 6;
  const int q = lane >> 4, l15 = lane & 15;
  const size_t row0 = (size_t)blockIdx.x * 128;
  const unsigned short* Wt = bw + BW_WT;
  const f32x4* g4 = (const f32x4*)(em + row0 * DD);

  f32x4 acc[2][3];
  f32x4 z4 = {0.f, 0.f, 0.f, 0.f};
  #pragma unroll
  for (int mt = 0; mt < 2; ++mt)
    #pragma unroll
    for (int nt = 0; nt < 3; ++nt) acc[mt][nt] = z4;

  int sr[4], sq[4];
  #pragma unroll
  for (int i = 0; i < 4; ++i) { int s = tid + i * 256; sr[i] = s >> 3; sq[i] = s & 7; }

  f32x4 pf[4];
  #pragma unroll
  for (int i = 0; i < 4; ++i)
    pf[i] = __builtin_nontemporal_load(g4 + sr[i] * 256 + sq[i]);
  bf16x8 Bf[3], Bn[3];
  #pragma unroll
  for (int nt = 0; nt < 3; ++nt)
    Bf[nt] = *(const bf16x8*)(Wt + (nt * 16 + l15) * 1024 + q * 8);

  for (int c = 0; c < 32; ++c) {
    #pragma unroll
    for (int i = 0; i < 4; ++i) {               // stage chunk c (cvt_pk -> b64)
      uint2 pk;
      pk.x = pk_bf16(pf[i][0], pf[i][1]);
      pk.y = pk_bf16(pf[i][2], pf[i][3]);
      *(uint2*)&At[c & 1][sr[i]][sq[i] * 4] = pk;
    }
    int cn = (c + 1 < 32) ? c + 1 : c;          // prefetch chunk c+1
    #pragma unroll
    for (int i = 0; i < 4; ++i)
      pf[i] = __builtin_nontemporal_load(g4 + sr[i] * 256 + cn * 8 + sq[i]);
    #pragma unroll
    for (int nt = 0; nt < 3; ++nt)
      Bn[nt] = *(const bf16x8*)(Wt + (nt * 16 + l15) * 1024 + cn * 32 + q * 8);
    lds_barrier();                              // drains ds_writes only
    bf16x8 Af[2];
    #pragma unroll
    for (int mt = 0; mt < 2; ++mt)
      Af[mt] = *(const bf16x8*)&At[c & 1][wv * 32 + mt * 16 + l15][q * 8];
    #pragma unroll
    for (int mt = 0; mt < 2; ++mt)
      #pragma unroll
      for (int nt = 0; nt < 3; ++nt)
        acc[mt][nt] = __builtin_amdgcn_mfma_f32_16x16x32_bf16(
            Af[mt], Bf[nt], acc[mt][nt], 0, 0, 0);
    #pragma unroll
    for (int nt = 0; nt < 3; ++nt) Bf[nt] = Bn[nt];
  }

  // epilogue: + bias, store cols<33 to logits, col 33 to bos
  #pragma unroll
  for (int nt = 0; nt < 3; ++nt) {
    int col = nt * 16 + l15;
    float bj = (col < NT) ? bias[col] : 0.0f;
    #pragma unroll
    for (int mt = 0; mt < 2; ++mt) {
      #pragma unroll
      for (int r = 0; r < 4; ++r) {
        float v = acc[mt][nt][r] + bj;
        size_t rg = row0 + wv * 32 + mt * 16 + q * 4 + r;
        if (col < 33) logits[rg * 33 + col] = v;
        else if (col == 33) bos[rg] = v;
      }
    }
  }
}

// ---------------- chunk transfer matrices (MFMA) + score ---------------------
// blocks 0..2047: (b,c) chunk matrix (32 steps), 1 wave. blocks 2048..: score.
// Single-wave blocks: DS ops are in-order per wave -> NO barriers anywhere
// (verified bit-identical in the round-3 fused variant).
__global__ __launch_bounds__(64) void chains_mat(
    const float* __restrict__ logits, const float* __restrict__ bos,
    const unsigned short* __restrict__ bw, const float* __restrict__ mask,
    const float* __restrict__ T, const int* __restrict__ tags,
    float* __restrict__ Pmat, float* __restrict__ CC,
    float* __restrict__ scorearr) {
  const int blk = blockIdx.x, lane = threadIdx.x;
  if (blk >= NB * NC) {                         // ---- supervised score ----
    int b = blk - NB * NC;
    float local = 0.0f;
    for (int t = lane; t < SS; t += 64) {
      if (t == 0) {
        int tg = tags[b * SS];
        local += T[BOSR * NT + tg] + logits[(size_t)(b * SS) * 33 + tg];
      } else {
        int tg = tags[b * SS + t];
        int tp = tags[b * SS + t - 1];
        float m = mask[b * SS + t];
        local += m * (logits[(size_t)(b * SS + t) * 33 + tg] + T[tp * NT + tg]);
      }
    }
    float w = warp_sum64(local);
    if (lane == 0) scorearr[b] = w;
    return;
  }

  __shared__ unsigned short S[48][72];          // P bf16, stride 72 (2-way max)
  __shared__ float eeL[32][52];                 // exp(emissions), 16B-aligned rows
  const int b = blk >> 5, c = blk & 31;
  const int q = lane >> 4, l15 = lane & 15;

  {                                             // zero S then identity (1 wave,
    unsigned long long* p = (unsigned long long*)&S[0][0];   // in-order DS)
    for (int i = lane; i < 864; i += 64) p[i] = 0ull;
  }
  if (lane < NT) S[lane][lane] = 0x3F80;        // bf16(1.0)

  int t = c * 32 + 1 + lane;                    // lanes 0..31 own one step each
  float mval = 0.0f;
  if (lane < 32) {
    if (t < SS) {
      size_t rg = (size_t)b * SS + t;
      #pragma unroll
      for (int j = 0; j < 33; ++j) eeL[lane][j] = __expf(logits[rg * 33 + j]);
      eeL[lane][33] = __expf(bos[rg]);
      #pragma unroll
      for (int j = 34; j < 48; ++j) eeL[lane][j] = 0.0f;
      mval = mask[rg];
    } else {
      #pragma unroll
      for (int j = 0; j < 48; ++j) eeL[lane][j] = 0.0f;
    }
  }
  unsigned long long mb = __ballot(mval > 0.5f); // step-active bits, SGPR pair

  bf16x8 Af[3][2];                              // static A = expT^T frags
  const unsigned short* eta = bw + BW_ETA;
  #pragma unroll
  for (int mt = 0; mt < 3; ++mt)
    #pragma unroll
    for (int kt = 0; kt < 2; ++kt)
      Af[mt][kt] = *(const bf16x8*)(eta + (mt * 16 + l15) * 64 + kt * 32 + q * 8);

  float Clog = 0.0f;
  f32x4 z4 = {0.f, 0.f, 0.f, 0.f};

  for (int tt = 0; tt < 32; ++tt) {
    if ((mb >> tt) & 1ull) {                    // SALU bit test, wave-uniform
      bf16x8 Bf[2][3];
      #pragma unroll
      for (int kt = 0; kt < 2; ++kt)
        #pragma unroll
        for (int nt = 0; nt < 3; ++nt)
          Bf[kt][nt] = *(const bf16x8*)&S[nt * 16 + l15][kt * 32 + q * 8];
      f32x4 acc[3][3];
      #pragma unroll
      for (int mt = 0; mt < 3; ++mt)
        #pragma unroll
        for (int nt = 0; nt < 3; ++nt) {
          acc[mt][nt] = __builtin_amdgcn_mfma_f32_16x16x32_bf16(
              Af[mt][0], Bf[0][nt], z4, 0, 0, 0);
          acc[mt][nt] = __builtin_amdgcn_mfma_f32_16x16x32_bf16(
              Af[mt][1], Bf[1][nt], acc[mt][nt], 0, 0, 0);
        }
      float r = rfl(acc[0][0][0]);              // D[0][0] = P_new[0][0] > 0
      float rin = __builtin_amdgcn_rcpf(r);
      Clog += __logf(r);
      #pragma unroll
      for (int mt = 0; mt < 3; ++mt) {
        f32x4 e4 = *(const f32x4*)&eeL[tt][mt * 16 + q * 4];
        e4 = e4 * rin;                          // combined col-scale * renorm
        #pragma unroll
        for (int nt = 0; nt < 3; ++nt) {
          f32x4 v = acc[mt][nt] * e4;
          uint2 pk;
          pk.x = pk_bf16(v[0], v[1]);
          pk.y = pk_bf16(v[2], v[3]);
          *(uint2*)&S[nt * 16 + l15][mt * 16 + q * 4] = pk;
        }
      }
    }
  }

  float* Pb = Pmat + (size_t)(b * NC + c) * (NP * NP);
  #pragma unroll
  for (int i = 0; i < 9; ++i) {                 // dump S -> f32 Pmat
    int flat = i * 64 + lane;                   // 0..575 float4 slots
    int n = flat / 12, qq = flat - n * 12;
    unsigned long long pk = *(unsigned long long*)&S[n][qq * 4];
    float4 o;
    o.x = bf2f((unsigned short)(pk));
    o.y = bf2f((unsigned short)(pk >> 16));
    o.z = bf2f((unsigned short)(pk >> 32));
    o.w = bf2f((unsigned short)(pk >> 48));
    *(float4*)&Pb[n * 48 + qq * 4] = o;
  }
  if (lane == 0) CC[b * NC + c] = Clog;
}

// ---------------- per-batch serial combine: Z_b ------------------------------
// 1 wave: register-prefetched Pmat (next chunk loads issue during current
// chunk's fmaf), CC broadcast via shfl, no barriers (per-wave DS in-order).
__global__ __launch_bounds__(64) void reduceZ(
    const float* __restrict__ logits, const float* __restrict__ bos,
    const float* __restrict__ T, const float* __restrict__ Pmat,
    const float* __restrict__ CC, float* __restrict__ Zarr) {
  __shared__ __align__(16) float shv[64];
  const int b = blockIdx.x, lane = threadIdx.x;
  float a0;
  if (lane < 33)       a0 = logits[(size_t)b * SS * 33 + lane] + T[BOSR * NT + lane];
  else if (lane == 33) a0 = bos[(size_t)b * SS] + T[BOSR * NT + 33];
  else                 a0 = -INFINITY;
  float K = rfl(a0);                            // lane0 finite
  float v = (lane < 48) ? __expf(a0 - K) : 0.0f;
  float C = K;
  float CCl = (lane < 32) ? CC[b * NC + lane] : 0.0f;
  const float* Pbase = Pmat + (size_t)b * NC * (NP * NP) + lane * 48;

  f32x4 Pp[12];                                 // prefetched chunk rows
  if (lane < 48) {
    #pragma unroll
    for (int i = 0; i < 12; ++i) Pp[i] = *(const f32x4*)(Pbase + i * 4);
  }
  for (int c = 0; c < NC; ++c) {
    shv[lane] = v;                              // in-order per wave
    f32x4 cur[12];
    #pragma unroll
    for (int i = 0; i < 12; ++i) cur[i] = Pp[i];
    if (c + 1 < NC && lane < 48) {              // prefetch next chunk
      #pragma unroll
      for (int i = 0; i < 12; ++i)
        Pp[i] = *(const f32x4*)(Pbase + (size_t)(c + 1) * (NP * NP) + i * 4);
    }
    float u = 0.0f;
    if (lane < 48) {
      float uu0 = 0.f, uu1 = 0.f, uu2 = 0.f, uu3 = 0.f;
      #pragma unroll
      for (int qq = 0; qq < 12; qq += 4) {
        f32x4 v0 = *(const f32x4*)&shv[qq * 4];
        f32x4 v1 = *(const f32x4*)&shv[qq * 4 + 4];
        f32x4 v2 = *(const f32x4*)&shv[qq * 4 + 8];
        f32x4 v3 = *(const f32x4*)&shv[qq * 4 + 12];
        uu0 = fmaf(cur[qq][0], v0[0], uu0);   uu0 = fmaf(cur[qq][1], v0[1], uu0);
        uu0 = fmaf(cur[qq][2], v0[2], uu0);   uu0 = fmaf(cur[qq][3], v0[3], uu0);
        uu1 = fmaf(cur[qq+1][0], v1[0], uu1); uu1 = fmaf(cur[qq+1][1], v1[1], uu1);
        uu1 = fmaf(cur[qq+1][2], v1[2], uu1); uu1 = fmaf(cur[qq+1][3], v1[3], uu1);
        uu2 = fmaf(cur[qq+2][0], v2[0], uu2); uu2 = fmaf(cur[qq+2][1], v2[1], uu2);
        uu2 = fmaf(cur[qq+2][2], v2[2], uu2); uu2 = fmaf(cur[qq+2][3], v2[3], uu2);
        uu3 = fmaf(cur[qq+3][0], v3[0], uu3); uu3 = fmaf(cur[qq+3][1], v3[1], uu3);
        uu3 = fmaf(cur[qq+3][2], v3[2], uu3); uu3 = fmaf(cur[qq+3][3], v3[3], uu3);
      }
      u = (uu0 + uu1) + (uu2 + uu3);
    }
    float r = rfl(u);                           // lane0: u > 0
    v = u * __builtin_amdgcn_rcpf(r);
    C += __logf(r) + __shfl(CCl, c, 64);
  }
  float s = warp_sum64(v);
  if (lane == 0) Zarr[b] = C + __logf(s);
}

// ---------------- final: loss = sum_b (Z_b - score_b) ------------------------
__global__ void finalk(const float* __restrict__ Zarr,
                       const float* __restrict__ sc, float* __restrict__ out) {
  float x = Zarr[threadIdx.x] - sc[threadIdx.x];
  float s = warp_sum64(x);
  if (threadIdx.x == 0) out[0] = s;
}

extern "C" void kernel_launch(void* const* d_in, const int* in_sizes, int n_in,
                              void* d_out, int out_size, void* d_ws, size_t ws_size,
                              hipStream_t stream) {
  const float* em   = (const float*)d_in[0];
  const int*   tags = (const int*)d_in[1];
  const float* mask = (const float*)d_in[2];
  const float* W    = (const float*)d_in[3];
  const float* bias = (const float*)d_in[4];
  const float* T    = (const float*)d_in[5];

  float* out = (float*)d_out;
  float* ws  = (float*)d_ws;
  float* bos   = ws + WS_BOS;
  float* Pmat  = ws + WS_PMAT;
  float* CC    = ws + WS_CC;
  float* Zarr  = ws + WS_Z;
  float* score = ws + WS_SC;
  unsigned short* bw = (unsigned short*)(ws + WS_BF16);
  float* logits = out + 1;                      // d_out = [loss, logits(B,S,33)]

  hipLaunchKernelGGL(prep, dim3(204), dim3(256), 0, stream, W, T, bw);
  hipLaunchKernelGGL(gemm_mfma, dim3(NB * SS / 128), dim3(256), 0, stream,
                     em, bw, bias, logits, bos);
  hipLaunchKernelGGL(chains_mat, dim3(NB * NC + NB), dim3(64), 0, stream,
                     logits, bos, bw, mask, T, tags, Pmat, CC, score);
  hipLaunchKernelGGL(reduceZ, dim3(NB), dim3(64), 0, stream,
                     logits, bos, T, Pmat, CC, Zarr);
  hipLaunchKernelGGL(finalk, dim3(1), dim3(64), 0, stream, Zarr, score, out);
}

// Round 5
// 415.710 us; speedup vs baseline: 1.0177x; 1.0034x over previous
//
#include <hip/hip_runtime.h>
#include <math.h>

#define SS 1024
#define DD 1024
#define NB 64
#define NT 34            // 33 tags + BOS
#define NP 48            // padded state count (3 x 16)
#define NC 32            // time chunks per sequence (32 steps each)
#define BOSR 33

typedef __attribute__((ext_vector_type(8))) short bf16x8;
typedef __attribute__((ext_vector_type(4))) float f32x4;

// ---- ws layout (float index) ----
#define WS_BOS   0                              // [65536] proj col 33
#define WS_PMAT  (WS_BOS + NB*SS)               // [64*32*2304] chunk matrices f32
#define WS_CC    (WS_PMAT + NB*NC*NP*NP)        // [2048] chunk log-renorm
#define WS_Z     (WS_CC + NB*NC)                // [64]
#define WS_SC    (WS_Z + NB)                    // [64]
#define WS_CNT   (WS_SC + NB)                   // [1] int done-counter
#define WS_BF16  (WS_CNT + 1)                   // bf16 region start (ushort*)
// bf16 region (ushort offsets)
#define BW_WT    0                              // Wt[48][1024]: W^T bf16, pad 0
#define BW_ETA   (48*1024)                      // expTA[48][64]: A[m][k]=exp(T[k][m])

__device__ __forceinline__ float warp_sum64(float x) {
  #pragma unroll
  for (int off = 32; off > 0; off >>= 1) x += __shfl_down(x, off, 64);
  return x;
}
__device__ __forceinline__ float rfl(float x) {
  return __int_as_float(__builtin_amdgcn_readfirstlane(__float_as_int(x)));
}
__device__ __forceinline__ unsigned short f2bf(float f) {  // RNE (prep only)
  unsigned int u = __float_as_uint(f);
  unsigned int r = u + 0x7fffu + ((u >> 16) & 1u);
  return (unsigned short)(r >> 16);
}
__device__ __forceinline__ float bf2f(unsigned short h) {
  return __uint_as_float(((unsigned int)h) << 16);
}
// 2x f32 -> packed 2x bf16 in one VALU op (gfx950 v_cvt_pk_bf16_f32, RNE)
__device__ __forceinline__ unsigned int pk_bf16(float a, float b) {
  unsigned int d;
  asm("v_cvt_pk_bf16_f32 %0, %1, %2" : "=v"(d) : "v"(a), "v"(b));
  return d;
}
// barrier that drains ONLY LDS ops (keeps global prefetch in flight)
__device__ __forceinline__ void lds_barrier() {
  asm volatile("s_waitcnt lgkmcnt(0)" ::: "memory");
  __builtin_amdgcn_s_barrier();
  __builtin_amdgcn_sched_barrier(0);
}

// ---------------- prep: Wt bf16 transpose + expTA + counter zero -------------
__global__ __launch_bounds__(256) void prep(const float* __restrict__ W,
                                            const float* __restrict__ T,
                                            unsigned short* __restrict__ bw,
                                            int* __restrict__ cnt) {
  int idx = blockIdx.x * 256 + threadIdx.x;
  if (idx == 0) *cnt = 0;                       // re-zero each graph replay
  if (idx < 48 * 1024) {                        // Wt[n][k] = W[k][n]
    int n = idx >> 10, k = idx & 1023;
    float v = (n < NT) ? W[k * NT + n] : 0.0f;
    bw[BW_WT + idx] = f2bf(v);
  } else if (idx < 48 * 1024 + 48 * 64) {       // expTA[m][k] = exp(T[k][m])
    int j = idx - 48 * 1024;
    int m = j >> 6, k = j & 63;
    float v = (m < NT && k < NT) ? __expf(T[k * NT + m]) : 0.0f;
    bw[BW_ETA + j] = f2bf(v);
  }
}

// ---------------- fused GEMM (LDS-staged, coalesced) + chunk chains ----------
// 512 blocks x 256 thr; block = 128 rows of one batch (= 4 chunks of 32 steps).
// GEMM phase: IDENTICAL structure to the verified 417µs kernel (double-buffered
// LDS staging, coalesced 128B-segment loads, lds_barrier). Chain phase: wave w
// owns chunk cg = ((row0&1023)>>5)+w, steps [32cg,32cg+31] (bit 0 cleared for
// cg==0); ee comes straight from accumulators (no logits re-read). Chain LDS
// is union'd over the dead At buffer; one full __syncthreads() between phases
// makes the aliasing safe. Chain phase is wave-private -> no further barriers.
__global__ __launch_bounds__(256) void gemm_chains(
    const float* __restrict__ em, const unsigned short* __restrict__ bw,
    const float* __restrict__ bias, const float* __restrict__ mask,
    float* __restrict__ logits, float* __restrict__ bos,
    float* __restrict__ Pmat, float* __restrict__ CC) {
  union SMem {
    unsigned short At[2][128][40];              // GEMM phase (20.5 KB)
    struct {
      unsigned short S[4][48][72];              // chain P bf16 (27.6 KB)
      float eeL[4][32][52];                     // chain exp(proj) (26.6 KB)
    } ch;
  };
  __shared__ __align__(16) SMem sm;
  const int tid = threadIdx.x;
  const int lane = tid & 63, wv = tid >> 6;
  const int q = lane >> 4, l15 = lane & 15;
  const size_t row0 = (size_t)blockIdx.x * 128;
  const int b = (int)(row0 >> 10);
  const int cg = (((int)(row0 & 1023)) >> 5) + wv;   // global chunk 0..31
  const unsigned short* Wt = bw + BW_WT;
  const f32x4* g4 = (const f32x4*)(em + row0 * DD);

  f32x4 acc[2][3];
  f32x4 z4 = {0.f, 0.f, 0.f, 0.f};
  #pragma unroll
  for (int mt = 0; mt < 2; ++mt)
    #pragma unroll
    for (int nt = 0; nt < 3; ++nt) acc[mt][nt] = z4;

  int sr[4], sq[4];
  #pragma unroll
  for (int i = 0; i < 4; ++i) { int s = tid + i * 256; sr[i] = s >> 3; sq[i] = s & 7; }

  f32x4 pf[4];
  #pragma unroll
  for (int i = 0; i < 4; ++i)
    pf[i] = __builtin_nontemporal_load(g4 + sr[i] * 256 + sq[i]);
  bf16x8 Bf[3], Bn[3];
  #pragma unroll
  for (int nt = 0; nt < 3; ++nt)
    Bf[nt] = *(const bf16x8*)(Wt + (nt * 16 + l15) * 1024 + q * 8);

  for (int c = 0; c < 32; ++c) {
    #pragma unroll
    for (int i = 0; i < 4; ++i) {               // stage chunk c (cvt_pk -> b64)
      uint2 pk;
      pk.x = pk_bf16(pf[i][0], pf[i][1]);
      pk.y = pk_bf16(pf[i][2], pf[i][3]);
      *(uint2*)&sm.At[c & 1][sr[i]][sq[i] * 4] = pk;
    }
    int cn = (c + 1 < 32) ? c + 1 : c;          // prefetch chunk c+1
    #pragma unroll
    for (int i = 0; i < 4; ++i)
      pf[i] = __builtin_nontemporal_load(g4 + sr[i] * 256 + cn * 8 + sq[i]);
    #pragma unroll
    for (int nt = 0; nt < 3; ++nt)
      Bn[nt] = *(const bf16x8*)(Wt + (nt * 16 + l15) * 1024 + cn * 32 + q * 8);
    lds_barrier();                              // drains ds_writes only
    bf16x8 Af[2];
    #pragma unroll
    for (int mt = 0; mt < 2; ++mt)
      Af[mt] = *(const bf16x8*)&sm.At[c & 1][wv * 32 + mt * 16 + l15][q * 8];
    #pragma unroll
    for (int mt = 0; mt < 2; ++mt)
      #pragma unroll
      for (int nt = 0; nt < 3; ++nt)
        acc[mt][nt] = __builtin_amdgcn_mfma_f32_16x16x32_bf16(
            Af[mt], Bf[nt], acc[mt][nt], 0, 0, 0);
    #pragma unroll
    for (int nt = 0; nt < 3; ++nt) Bf[nt] = Bn[nt];
  }

  __syncthreads();                              // At dead; ch may now alias it

  // ---- epilogue: bias, store logits/bos, ee -> per-wave LDS slab ----
  #pragma unroll
  for (int nt = 0; nt < 3; ++nt) {
    int col = nt * 16 + l15;
    float bj = (col < NT) ? bias[col] : 0.0f;
    #pragma unroll
    for (int mt = 0; mt < 2; ++mt) {
      #pragma unroll
      for (int r = 0; r < 4; ++r) {
        float v = acc[mt][nt][r] + bj;
        size_t rg = row0 + wv * 32 + mt * 16 + q * 4 + r;
        if (col < 33) logits[rg * 33 + col] = v;
        else if (col == 33) bos[rg] = v;
        sm.ch.eeL[wv][mt * 16 + q * 4 + r][col] = (col < NT) ? __expf(v) : 0.0f;
      }
    }
  }

  float mval = 0.0f;                            // step-active mask (this chunk)
  if (lane < 32) mval = mask[row0 + wv * 32 + lane];
  unsigned long long mb = __ballot(mval > 0.5f);
  if (cg == 0) mb &= ~1ull;                     // step 0 is in alpha_0

  {                                             // zero per-wave S then identity
    unsigned long long* p = (unsigned long long*)&sm.ch.S[wv][0][0]; // 864 qw
    for (int i = lane; i < 864; i += 64) p[i] = 0ull;
  }
  if (lane < NT) sm.ch.S[wv][lane][lane] = 0x3F80;  // bf16(1.0)

  bf16x8 Ef[3][2];                              // static A = expT^T frags
  const unsigned short* eta = bw + BW_ETA;
  #pragma unroll
  for (int mt = 0; mt < 3; ++mt)
    #pragma unroll
    for (int kt = 0; kt < 2; ++kt)
      Ef[mt][kt] = *(const bf16x8*)(eta + (mt * 16 + l15) * 64 + kt * 32 + q * 8);

  float Clog = 0.0f;
  for (int tt = 0; tt < 32; ++tt) {
    if ((mb >> tt) & 1ull) {                    // SALU bit test, wave-uniform
      bf16x8 Bq[2][3];
      #pragma unroll
      for (int kt = 0; kt < 2; ++kt)
        #pragma unroll
        for (int nt = 0; nt < 3; ++nt)
          Bq[kt][nt] = *(const bf16x8*)&sm.ch.S[wv][nt * 16 + l15][kt * 32 + q * 8];
      f32x4 pacc[3][3];
      #pragma unroll
      for (int mt = 0; mt < 3; ++mt)
        #pragma unroll
        for (int nt = 0; nt < 3; ++nt) {
          pacc[mt][nt] = __builtin_amdgcn_mfma_f32_16x16x32_bf16(
              Ef[mt][0], Bq[0][nt], z4, 0, 0, 0);
          pacc[mt][nt] = __builtin_amdgcn_mfma_f32_16x16x32_bf16(
              Ef[mt][1], Bq[1][nt], pacc[mt][nt], 0, 0, 0);
        }
      float r = rfl(pacc[0][0][0]);             // P_new[0][0] > 0
      float rin = __builtin_amdgcn_rcpf(r);
      Clog += __logf(r);
      #pragma unroll
      for (int mt = 0; mt < 3; ++mt) {
        f32x4 e4 = *(const f32x4*)&sm.ch.eeL[wv][tt][mt * 16 + q * 4];
        e4 = e4 * rin;                          // combined col-scale * renorm
        #pragma unroll
        for (int nt = 0; nt < 3; ++nt) {
          f32x4 v = pacc[mt][nt] * e4;
          uint2 pk;
          pk.x = pk_bf16(v[0], v[1]);
          pk.y = pk_bf16(v[2], v[3]);
          *(uint2*)&sm.ch.S[wv][nt * 16 + l15][mt * 16 + q * 4] = pk;
        }
      }
    }
  }

  float* Pb = Pmat + (size_t)(b * NC + cg) * (NP * NP);
  #pragma unroll
  for (int i = 0; i < 9; ++i) {                 // dump S -> f32 Pmat
    int flat = i * 64 + lane;                   // 0..575 float4 slots
    int n = flat / 12, qq = flat - n * 12;
    unsigned long long pk = *(unsigned long long*)&sm.ch.S[wv][n][qq * 4];
    float4 o;
    o.x = bf2f((unsigned short)(pk));
    o.y = bf2f((unsigned short)(pk >> 16));
    o.z = bf2f((unsigned short)(pk >> 32));
    o.w = bf2f((unsigned short)(pk >> 48));
    *(float4*)&Pb[n * 48 + qq * 4] = o;
  }
  if (lane == 0) CC[b * NC + cg] = Clog;
}

// ---------------- per-batch combine + score + fused final --------------------
// 64 blocks x 128 thr. wave 0: Z_b serial combine (register-prefetched Pmat,
// shfl'd CC, no barriers). wave 1: supervised path score. Last block (device-
// scope atomic counter) computes loss = sum_b(Z_b - score_b).
__global__ __launch_bounds__(128) void reduceZ(
    const float* __restrict__ logits, const float* __restrict__ bos,
    const float* __restrict__ T, const float* __restrict__ Pmat,
    const float* __restrict__ CC, const int* __restrict__ tags,
    const float* __restrict__ mask, float* __restrict__ Zarr,
    float* __restrict__ scorearr, int* __restrict__ cnt,
    float* __restrict__ out) {
  const int b = blockIdx.x;
  const int tid = threadIdx.x;
  const int lane = tid & 63;
  __shared__ __align__(16) float shv[64];
  __shared__ int lastflag;

  if (tid >= 64) {                              // ---- score wave ----
    float local = 0.0f;
    for (int t = lane; t < SS; t += 64) {
      if (t == 0) {
        int tg = tags[b * SS];
        local += T[BOSR * NT + tg] + logits[(size_t)(b * SS) * 33 + tg];
      } else {
        int tg = tags[b * SS + t];
        int tp = tags[b * SS + t - 1];
        float m = mask[b * SS + t];
        local += m * (logits[(size_t)(b * SS + t) * 33 + tg] + T[tp * NT + tg]);
      }
    }
    float w = warp_sum64(local);
    if (lane == 0) scorearr[b] = w;
  } else {                                      // ---- Z combine wave ----
    float a0;
    if (lane < 33)       a0 = logits[(size_t)b * SS * 33 + lane] + T[BOSR * NT + lane];
    else if (lane == 33) a0 = bos[(size_t)b * SS] + T[BOSR * NT + 33];
    else                 a0 = -INFINITY;
    float K = rfl(a0);                          // lane0 finite
    float v = (lane < 48) ? __expf(a0 - K) : 0.0f;
    float C = K;
    float CCl = (lane < 32) ? CC[b * NC + lane] : 0.0f;
    const float* Pbase = Pmat + (size_t)b * NC * (NP * NP) + lane * 48;

    f32x4 Pp[12];                               // prefetched chunk rows
    if (lane < 48) {
      #pragma unroll
      for (int i = 0; i < 12; ++i) Pp[i] = *(const f32x4*)(Pbase + i * 4);
    }
    for (int c = 0; c < NC; ++c) {
      shv[lane] = v;                            // in-order per wave
      f32x4 cur[12];
      #pragma unroll
      for (int i = 0; i < 12; ++i) cur[i] = Pp[i];
      if (c + 1 < NC && lane < 48) {            // prefetch next chunk
        #pragma unroll
        for (int i = 0; i < 12; ++i)
          Pp[i] = *(const f32x4*)(Pbase + (size_t)(c + 1) * (NP * NP) + i * 4);
      }
      float u = 0.0f;
      if (lane < 48) {
        float uu0 = 0.f, uu1 = 0.f, uu2 = 0.f, uu3 = 0.f;
        #pragma unroll
        for (int qq = 0; qq < 12; qq += 4) {
          f32x4 v0 = *(const f32x4*)&shv[qq * 4];
          f32x4 v1 = *(const f32x4*)&shv[qq * 4 + 4];
          f32x4 v2 = *(const f32x4*)&shv[qq * 4 + 8];
          f32x4 v3 = *(const f32x4*)&shv[qq * 4 + 12];
          uu0 = fmaf(cur[qq][0], v0[0], uu0);   uu0 = fmaf(cur[qq][1], v0[1], uu0);
          uu0 = fmaf(cur[qq][2], v0[2], uu0);   uu0 = fmaf(cur[qq][3], v0[3], uu0);
          uu1 = fmaf(cur[qq+1][0], v1[0], uu1); uu1 = fmaf(cur[qq+1][1], v1[1], uu1);
          uu1 = fmaf(cur[qq+1][2], v1[2], uu1); uu1 = fmaf(cur[qq+1][3], v1[3], uu1);
          uu2 = fmaf(cur[qq+2][0], v2[0], uu2); uu2 = fmaf(cur[qq+2][1], v2[1], uu2);
          uu2 = fmaf(cur[qq+2][2], v2[2], uu2); uu2 = fmaf(cur[qq+2][3], v2[3], uu2);
          uu3 = fmaf(cur[qq+3][0], v3[0], uu3); uu3 = fmaf(cur[qq+3][1], v3[1], uu3);
          uu3 = fmaf(cur[qq+3][2], v3[2], uu3); uu3 = fmaf(cur[qq+3][3], v3[3], uu3);
        }
        u = (uu0 + uu1) + (uu2 + uu3);
      }
      float r = rfl(u);                         // lane0: u > 0
      v = u * __builtin_amdgcn_rcpf(r);
      C += __logf(r) + __shfl(CCl, c, 64);
    }
    float s = warp_sum64(v);
    if (lane == 0) Zarr[b] = C + __logf(s);
  }

  __syncthreads();
  if (tid == 0) {                               // release + count
    __threadfence();
    lastflag = (atomicAdd(cnt, 1) == NB - 1);
  }
  __syncthreads();
  if (lastflag && tid < 64) {                   // last block: final sum
    __threadfence();                            // acquire
    float x = Zarr[tid] - scorearr[tid];
    float s2 = warp_sum64(x);
    if (tid == 0) out[0] = s2;
  }
}

extern "C" void kernel_launch(void* const* d_in, const int* in_sizes, int n_in,
                              void* d_out, int out_size, void* d_ws, size_t ws_size,
                              hipStream_t stream) {
  const float* em   = (const float*)d_in[0];
  const int*   tags = (const int*)d_in[1];
  const float* mask = (const float*)d_in[2];
  const float* W    = (const float*)d_in[3];
  const float* bias = (const float*)d_in[4];
  const float* T    = (const float*)d_in[5];

  float* out = (float*)d_out;
  float* ws  = (float*)d_ws;
  float* bos   = ws + WS_BOS;
  float* Pmat  = ws + WS_PMAT;
  float* CC    = ws + WS_CC;
  float* Zarr  = ws + WS_Z;
  float* score = ws + WS_SC;
  int*   cnt   = (int*)(ws + WS_CNT);
  unsigned short* bw = (unsigned short*)(ws + WS_BF16);
  float* logits = out + 1;                      // d_out = [loss, logits(B,S,33)]

  hipLaunchKernelGGL(prep, dim3(204), dim3(256), 0, stream, W, T, bw, cnt);
  hipLaunchKernelGGL(gemm_chains, dim3(NB * SS / 128), dim3(256), 0, stream,
                     em, bw, bias, mask, logits, bos, Pmat, CC);
  hipLaunchKernelGGL(reduceZ, dim3(NB), dim3(128), 0, stream,
                     logits, bos, T, Pmat, CC, tags, mask, Zarr, score, cnt, out);
}

// Round 7
// 409.733 us; speedup vs baseline: 1.0326x; 1.0146x over previous
//
#include <hip/hip_runtime.h>
#include <math.h>

#define SS 1024
#define DD 1024
#define NB 64
#define NT 34            // 33 tags + BOS
#define NP 48            // padded state count (3 x 16)
#define NC 32            // time chunks per sequence (32 steps each)
#define BOSR 33

typedef __attribute__((ext_vector_type(8))) short bf16x8;
typedef __attribute__((ext_vector_type(4))) float f32x4;
typedef __attribute__((ext_vector_type(4))) unsigned int u32x4;

// ---- ws layout (float index) ----
#define WS_BOS   0                              // [65536] proj col 33
#define WS_PMAT  (WS_BOS + NB*SS)               // [64*32*2304 ushort] chunk mats bf16
#define WS_CC    (WS_PMAT + NB*NC*1152)         // [2048] chunk log-renorm
#define WS_Z     (WS_CC + NB*NC)                // [64]
#define WS_SC    (WS_Z + NB)                    // [64]
#define WS_CNT   (WS_SC + NB)                   // [1] int done-counter
#define WS_BF16  (WS_CNT + 1)                   // bf16 region start (ushort*)
// bf16 region (ushort offsets)
#define BW_WT    0                              // Wt[48][1024]: W^T bf16, pad 0
#define BW_ETA   (48*1024)                      // expTA[48][64]: A[m][k]=exp(T[k][m])

__device__ __forceinline__ float warp_sum64(float x) {
  #pragma unroll
  for (int off = 32; off > 0; off >>= 1) x += __shfl_down(x, off, 64);
  return x;
}
__device__ __forceinline__ float rfl(float x) {
  return __int_as_float(__builtin_amdgcn_readfirstlane(__float_as_int(x)));
}
__device__ __forceinline__ unsigned short f2bf(float f) {  // RNE (prep only)
  unsigned int u = __float_as_uint(f);
  unsigned int r = u + 0x7fffu + ((u >> 16) & 1u);
  return (unsigned short)(r >> 16);
}
// packed bf16 dword -> two exact f32
__device__ __forceinline__ float bflo(unsigned int d) {
  return __uint_as_float(d << 16);
}
__device__ __forceinline__ float bfhi(unsigned int d) {
  return __uint_as_float(d & 0xffff0000u);
}
// 2x f32 -> packed 2x bf16 in one VALU op (gfx950 v_cvt_pk_bf16_f32, RNE)
__device__ __forceinline__ unsigned int pk_bf16(float a, float b) {
  unsigned int d;
  asm("v_cvt_pk_bf16_f32 %0, %1, %2" : "=v"(d) : "v"(a), "v"(b));
  return d;
}
// barrier that drains ONLY LDS ops (keeps global prefetch in flight)
__device__ __forceinline__ void lds_barrier() {
  asm volatile("s_waitcnt lgkmcnt(0)" ::: "memory");
  __builtin_amdgcn_s_barrier();
  __builtin_amdgcn_sched_barrier(0);
}

// ---------------- prep: Wt bf16 transpose + expTA + counter zero -------------
__global__ __launch_bounds__(256) void prep(const float* __restrict__ W,
                                            const float* __restrict__ T,
                                            unsigned short* __restrict__ bw,
                                            int* __restrict__ cnt) {
  int idx = blockIdx.x * 256 + threadIdx.x;
  if (idx == 0) *cnt = 0;                       // re-zero each graph replay
  if (idx < 48 * 1024) {                        // Wt[n][k] = W[k][n]
    int n = idx >> 10, k = idx & 1023;
    float v = (n < NT) ? W[k * NT + n] : 0.0f;
    bw[BW_WT + idx] = f2bf(v);
  } else if (idx < 48 * 1024 + 48 * 64) {       // expTA[m][k] = exp(T[k][m])
    int j = idx - 48 * 1024;
    int m = j >> 6, k = j & 63;
    float v = (m < NT && k < NT) ? __expf(T[k * NT + m]) : 0.0f;
    bw[BW_ETA + j] = f2bf(v);
  }
}

// ---------------- fused GEMM (LDS-staged, coalesced) + chunk chains ----------
// 512 blocks x 256 thr; block = 128 rows of one batch (= 4 chunks of 32 steps).
// GEMM phase: verified coalesced double-buffered LDS staging + lds_barrier.
// Chain phase: wave w owns chunk cg, ee straight from accumulators; chain LDS
// union'd over dead At; wave-private -> no barriers after the phase switch.
// Pmat is dumped as RAW bf16 (S already is bf16): halves HBM both directions.
__global__ __launch_bounds__(256) void gemm_chains(
    const float* __restrict__ em, const unsigned short* __restrict__ bw,
    const float* __restrict__ bias, const float* __restrict__ mask,
    float* __restrict__ logits, float* __restrict__ bos,
    unsigned short* __restrict__ Pmat, float* __restrict__ CC) {
  union SMem {
    unsigned short At[2][128][40];              // GEMM phase (20.5 KB)
    struct {
      unsigned short S[4][48][72];              // chain P bf16 (27.6 KB)
      float eeL[4][32][52];                     // chain exp(proj) (26.6 KB)
    } ch;
  };
  __shared__ __align__(16) SMem sm;
  const int tid = threadIdx.x;
  const int lane = tid & 63, wv = tid >> 6;
  const int q = lane >> 4, l15 = lane & 15;
  const size_t row0 = (size_t)blockIdx.x * 128;
  const int b = (int)(row0 >> 10);
  const int cg = (((int)(row0 & 1023)) >> 5) + wv;   // global chunk 0..31
  const unsigned short* Wt = bw + BW_WT;
  const f32x4* g4 = (const f32x4*)(em + row0 * DD);

  f32x4 acc[2][3];
  f32x4 z4 = {0.f, 0.f, 0.f, 0.f};
  #pragma unroll
  for (int mt = 0; mt < 2; ++mt)
    #pragma unroll
    for (int nt = 0; nt < 3; ++nt) acc[mt][nt] = z4;

  int sr[4], sq[4];
  #pragma unroll
  for (int i = 0; i < 4; ++i) { int s = tid + i * 256; sr[i] = s >> 3; sq[i] = s & 7; }

  f32x4 pf[4];
  #pragma unroll
  for (int i = 0; i < 4; ++i)
    pf[i] = __builtin_nontemporal_load(g4 + sr[i] * 256 + sq[i]);
  bf16x8 Bf[3], Bn[3];
  #pragma unroll
  for (int nt = 0; nt < 3; ++nt)
    Bf[nt] = *(const bf16x8*)(Wt + (nt * 16 + l15) * 1024 + q * 8);

  for (int c = 0; c < 32; ++c) {
    #pragma unroll
    for (int i = 0; i < 4; ++i) {               // stage chunk c (cvt_pk -> b64)
      uint2 pk;
      pk.x = pk_bf16(pf[i][0], pf[i][1]);
      pk.y = pk_bf16(pf[i][2], pf[i][3]);
      *(uint2*)&sm.At[c & 1][sr[i]][sq[i] * 4] = pk;
    }
    int cn = (c + 1 < 32) ? c + 1 : c;          // prefetch chunk c+1
    #pragma unroll
    for (int i = 0; i < 4; ++i)
      pf[i] = __builtin_nontemporal_load(g4 + sr[i] * 256 + cn * 8 + sq[i]);
    #pragma unroll
    for (int nt = 0; nt < 3; ++nt)
      Bn[nt] = *(const bf16x8*)(Wt + (nt * 16 + l15) * 1024 + cn * 32 + q * 8);
    lds_barrier();                              // drains ds_writes only
    bf16x8 Af[2];
    #pragma unroll
    for (int mt = 0; mt < 2; ++mt)
      Af[mt] = *(const bf16x8*)&sm.At[c & 1][wv * 32 + mt * 16 + l15][q * 8];
    #pragma unroll
    for (int mt = 0; mt < 2; ++mt)
      #pragma unroll
      for (int nt = 0; nt < 3; ++nt)
        acc[mt][nt] = __builtin_amdgcn_mfma_f32_16x16x32_bf16(
            Af[mt], Bf[nt], acc[mt][nt], 0, 0, 0);
    #pragma unroll
    for (int nt = 0; nt < 3; ++nt) Bf[nt] = Bn[nt];
  }

  __syncthreads();                              // At dead; ch may now alias it

  // ---- epilogue: bias, store logits/bos, ee -> per-wave LDS slab ----
  #pragma unroll
  for (int nt = 0; nt < 3; ++nt) {
    int col = nt * 16 + l15;
    float bj = (col < NT) ? bias[col] : 0.0f;
    #pragma unroll
    for (int mt = 0; mt < 2; ++mt) {
      #pragma unroll
      for (int r = 0; r < 4; ++r) {
        float v = acc[mt][nt][r] + bj;
        size_t rg = row0 + wv * 32 + mt * 16 + q * 4 + r;
        if (col < 33) logits[rg * 33 + col] = v;
        else if (col == 33) bos[rg] = v;
        sm.ch.eeL[wv][mt * 16 + q * 4 + r][col] = (col < NT) ? __expf(v) : 0.0f;
      }
    }
  }

  float mval = 0.0f;                            // step-active mask (this chunk)
  if (lane < 32) mval = mask[row0 + wv * 32 + lane];
  unsigned long long mb = __ballot(mval > 0.5f);
  if (cg == 0) mb &= ~1ull;                     // step 0 is in alpha_0

  {                                             // zero per-wave S then identity
    unsigned long long* p = (unsigned long long*)&sm.ch.S[wv][0][0]; // 864 qw
    for (int i = lane; i < 864; i += 64) p[i] = 0ull;
  }
  if (lane < NT) sm.ch.S[wv][lane][lane] = 0x3F80;  // bf16(1.0)

  bf16x8 Ef[3][2];                              // static A = expT^T frags
  const unsigned short* eta = bw + BW_ETA;
  #pragma unroll
  for (int mt = 0; mt < 3; ++mt)
    #pragma unroll
    for (int kt = 0; kt < 2; ++kt)
      Ef[mt][kt] = *(const bf16x8*)(eta + (mt * 16 + l15) * 64 + kt * 32 + q * 8);

  float Clog = 0.0f;
  for (int tt = 0; tt < 32; ++tt) {
    if ((mb >> tt) & 1ull) {                    // SALU bit test, wave-uniform
      bf16x8 Bq[2][3];
      #pragma unroll
      for (int kt = 0; kt < 2; ++kt)
        #pragma unroll
        for (int nt = 0; nt < 3; ++nt)
          Bq[kt][nt] = *(const bf16x8*)&sm.ch.S[wv][nt * 16 + l15][kt * 32 + q * 8];
      f32x4 pacc[3][3];
      #pragma unroll
      for (int mt = 0; mt < 3; ++mt)
        #pragma unroll
        for (int nt = 0; nt < 3; ++nt) {
          pacc[mt][nt] = __builtin_amdgcn_mfma_f32_16x16x32_bf16(
              Ef[mt][0], Bq[0][nt], z4, 0, 0, 0);
          pacc[mt][nt] = __builtin_amdgcn_mfma_f32_16x16x32_bf16(
              Ef[mt][1], Bq[1][nt], pacc[mt][nt], 0, 0, 0);
        }
      float r = rfl(pacc[0][0][0]);             // P_new[0][0] > 0
      float rin = __builtin_amdgcn_rcpf(r);
      Clog += __logf(r);
      #pragma unroll
      for (int mt = 0; mt < 3; ++mt) {
        f32x4 e4 = *(const f32x4*)&sm.ch.eeL[wv][tt][mt * 16 + q * 4];
        e4 = e4 * rin;                          // combined col-scale * renorm
        #pragma unroll
        for (int nt = 0; nt < 3; ++nt) {
          f32x4 v = pacc[mt][nt] * e4;
          uint2 pk;
          pk.x = pk_bf16(v[0], v[1]);
          pk.y = pk_bf16(v[2], v[3]);
          *(uint2*)&sm.ch.S[wv][nt * 16 + l15][mt * 16 + q * 4] = pk;
        }
      }
    }
  }

  // dump S -> Pmat as RAW bf16 (288 uint4 slots of 8 ushorts each)
  unsigned short* Pb = Pmat + (size_t)(b * NC + cg) * 2304;
  #pragma unroll
  for (int i = 0; i < 5; ++i) {
    int flat = i * 64 + lane;                   // 0..319, valid < 288
    if (flat < 288) {
      int n = flat / 6, qq = flat - n * 6;      // row n, 8-ushort group qq
      u32x4 d = *(const u32x4*)&sm.ch.S[wv][n][qq * 8];
      *(u32x4*)(Pb + n * 48 + qq * 8) = d;
    }
  }
  if (lane == 0) CC[b * NC + cg] = Clog;
}

// ---------------- per-batch combine + score + fused final --------------------
// 64 blocks x 128 thr. wave 0: Z_b serial combine over bf16 Pmat with 2-deep
// named double-buffer prefetch (load->use distance ~2 chunks), shfl'd CC, no
// barriers in the serial loop. wave 1: supervised path score. Last block
// (device-scope atomic counter) computes loss = sum_b(Z_b - score_b).
__global__ __launch_bounds__(128) void reduceZ(
    const float* __restrict__ logits, const float* __restrict__ bos,
    const float* __restrict__ T, const unsigned short* __restrict__ Pmat,
    const float* __restrict__ CC, const int* __restrict__ tags,
    const float* __restrict__ mask, float* __restrict__ Zarr,
    float* __restrict__ scorearr, int* __restrict__ cnt,
    float* __restrict__ out) {
  const int b = blockIdx.x;
  const int tid = threadIdx.x;
  const int lane = tid & 63;
  __shared__ __align__(16) float shv[64];
  __shared__ int lastflag;

  if (tid >= 64) {                              // ---- score wave ----
    float local = 0.0f;
    for (int t = lane; t < SS; t += 64) {
      if (t == 0) {
        int tg = tags[b * SS];
        local += T[BOSR * NT + tg] + logits[(size_t)(b * SS) * 33 + tg];
      } else {
        int tg = tags[b * SS + t];
        int tp = tags[b * SS + t - 1];
        float m = mask[b * SS + t];
        local += m * (logits[(size_t)(b * SS + t) * 33 + tg] + T[tp * NT + tg]);
      }
    }
    float w = warp_sum64(local);
    if (lane == 0) scorearr[b] = w;
  } else {                                      // ---- Z combine wave ----
    float a0;
    if (lane < 33)       a0 = logits[(size_t)b * SS * 33 + lane] + T[BOSR * NT + lane];
    else if (lane == 33) a0 = bos[(size_t)b * SS] + T[BOSR * NT + 33];
    else                 a0 = -INFINITY;
    float K = rfl(a0);                          // lane0 finite
    float v = (lane < 48) ? __expf(a0 - K) : 0.0f;
    float C = K;
    float CCl = (lane < 32) ? CC[b * NC + lane] : 0.0f;
    const unsigned short* Pr = Pmat + (size_t)b * NC * 2304 + lane * 48;

    u32x4 PA[6], PB[6];                         // 2-deep named double-buffer
    if (lane < 48) {
      #pragma unroll
      for (int i = 0; i < 6; ++i) PA[i] = *(const u32x4*)(Pr + i * 8);
      #pragma unroll
      for (int i = 0; i < 6; ++i) PB[i] = *(const u32x4*)(Pr + 2304 + i * 8);
    }

    // one combine step; FP summation order identical to the f32 version:
    // uu0: k{0-3,16-19,32-35}  uu1: k{4-7,...}  uu2: k{8-11,...}  uu3: k{12-15,...}
    #define COMBINE(BUF, c)                                                    \
    {                                                                          \
      shv[lane] = v;  /* in-order per wave */                                  \
      float u = 0.0f;                                                          \
      if (lane < 48) {                                                         \
        float uu0 = 0.f, uu1 = 0.f, uu2 = 0.f, uu3 = 0.f;                      \
        _Pragma("unroll")                                                      \
        for (int g = 0; g < 3; ++g) {                                          \
          u32x4 Pa = BUF[2 * g], Pc = BUF[2 * g + 1];                          \
          f32x4 v0 = *(const f32x4*)&shv[g * 16];                              \
          f32x4 v1 = *(const f32x4*)&shv[g * 16 + 4];                          \
          f32x4 v2 = *(const f32x4*)&shv[g * 16 + 8];                          \
          f32x4 v3 = *(const f32x4*)&shv[g * 16 + 12];                         \
          uu0 = fmaf(bflo(Pa[0]), v0[0], uu0); uu0 = fmaf(bfhi(Pa[0]), v0[1], uu0); \
          uu0 = fmaf(bflo(Pa[1]), v0[2], uu0); uu0 = fmaf(bfhi(Pa[1]), v0[3], uu0); \
          uu1 = fmaf(bflo(Pa[2]), v1[0], uu1); uu1 = fmaf(bfhi(Pa[2]), v1[1], uu1); \
          uu1 = fmaf(bflo(Pa[3]), v1[2], uu1); uu1 = fmaf(bfhi(Pa[3]), v1[3], uu1); \
          uu2 = fmaf(bflo(Pc[0]), v2[0], uu2); uu2 = fmaf(bfhi(Pc[0]), v2[1], uu2); \
          uu2 = fmaf(bflo(Pc[1]), v2[2], uu2); uu2 = fmaf(bfhi(Pc[1]), v2[3], uu2); \
          uu3 = fmaf(bflo(Pc[2]), v3[0], uu3); uu3 = fmaf(bfhi(Pc[2]), v3[1], uu3); \
          uu3 = fmaf(bflo(Pc[3]), v3[2], uu3); uu3 = fmaf(bfhi(Pc[3]), v3[3], uu3); \
        }                                                                      \
        u = (uu0 + uu1) + (uu2 + uu3);                                         \
      }                                                                        \
      float r = rfl(u);                                                        \
      v = u * __builtin_amdgcn_rcpf(r);                                        \
      C += __logf(r) + __shfl(CCl, (c), 64);                                   \
    }

    for (int cc = 0; cc < NC / 2; ++cc) {
      int c0 = 2 * cc;
      COMBINE(PA, c0);
      if (c0 + 2 < NC && lane < 48) {           // reload A for chunk c0+2
        #pragma unroll
        for (int i = 0; i < 6; ++i)
          PA[i] = *(const u32x4*)(Pr + (size_t)(c0 + 2) * 2304 + i * 8);
      }
      COMBINE(PB, c0 + 1);
      if (c0 + 3 < NC && lane < 48) {           // reload B for chunk c0+3
        #pragma unroll
        for (int i = 0; i < 6; ++i)
          PB[i] = *(const u32x4*)(Pr + (size_t)(c0 + 3) * 2304 + i * 8);
      }
    }
    #undef COMBINE
    float s = warp_sum64(v);
    if (lane == 0) Zarr[b] = C + __logf(s);
  }

  __syncthreads();
  if (tid == 0) {                               // release + count
    __threadfence();
    lastflag = (atomicAdd(cnt, 1) == NB - 1);
  }
  __syncthreads();
  if (lastflag && tid < 64) {                   // last block: final sum
    __threadfence();                            // acquire
    float x = Zarr[tid] - scorearr[tid];
    float s2 = warp_sum64(x);
    if (tid == 0) out[0] = s2;
  }
}

extern "C" void kernel_launch(void* const* d_in, const int* in_sizes, int n_in,
                              void* d_out, int out_size, void* d_ws, size_t ws_size,
                              hipStream_t stream) {
  const float* em   = (const float*)d_in[0];
  const int*   tags = (const int*)d_in[1];
  const float* mask = (const float*)d_in[2];
  const float* W    = (const float*)d_in[3];
  const float* bias = (const float*)d_in[4];
  const float* T    = (const float*)d_in[5];

  float* out = (float*)d_out;
  float* ws  = (float*)d_ws;
  float* bos   = ws + WS_BOS;
  unsigned short* Pmat16 = (unsigned short*)(ws + WS_PMAT);
  float* CC    = ws + WS_CC;
  float* Zarr  = ws + WS_Z;
  float* score = ws + WS_SC;
  int*   cnt   = (int*)(ws + WS_CNT);
  unsigned short* bw = (unsigned short*)(ws + WS_BF16);
  float* logits = out + 1;                      // d_out = [loss, logits(B,S,33)]

  hipLaunchKernelGGL(prep, dim3(204), dim3(256), 0, stream, W, T, bw, cnt);
  hipLaunchKernelGGL(gemm_chains, dim3(NB * SS / 128), dim3(256), 0, stream,
                     em, bw, bias, mask, logits, bos, Pmat16, CC);
  hipLaunchKernelGGL(reduceZ, dim3(NB), dim3(128), 0, stream,
                     logits, bos, T, Pmat16, CC, tags, mask, Zarr, score, cnt, out);
}